// Round 7
// baseline (286.870 us; speedup 1.0000x reference)
//
#include <hip/hip_runtime.h>
#include <hip/hip_bf16.h>

// Problem constants (fixed shapes from setup_inputs)
#define NROWS 65536   // 64*32*32
#define DIM   256
#define KCODE 1024
#define NUMEL (NROWS * DIM)   // 16777216
#define MARGIN 0.25f          // ~8 sigma of f16-MFMA distance noise
#define RG 16                 // rescue: flagged rows per block-group (v3: 8->16)

typedef _Float16 half8 __attribute__((ext_vector_type(8)));
typedef float    f32x4 __attribute__((ext_vector_type(4)));

// ---------------- prep: E^T fp32 (gather) + E^T f16 (MFMA) ----------------
// emb [DIM][KCODE] row-major -> et [KCODE][DIM] fp32, ef [KCODE][DIM] f16
__global__ __launch_bounds__(256) void vq_prep_te(const float* __restrict__ emb,
                                                  float* __restrict__ et,
                                                  _Float16* __restrict__ ef) {
    __shared__ float t[32][33];
    int bk = blockIdx.x & 31;   // k-tile
    int bd = blockIdx.x >> 5;   // d-tile
    int lx = threadIdx.x & 31;
    int ly = threadIdx.x >> 5;
#pragma unroll
    for (int i = 0; i < 4; ++i)
        t[ly + i * 8][lx] = emb[(bd * 32 + ly + i * 8) * KCODE + bk * 32 + lx];
    __syncthreads();
#pragma unroll
    for (int i = 0; i < 4; ++i) {
        float v = t[lx][ly + i * 8];
        int o = (bk * 32 + ly + i * 8) * DIM + bd * 32 + lx;
        et[o] = v;
        ef[o] = (_Float16)v;   // RNE
    }
}

// ---------------- prep: cn[k] = np.sum(emb*emb, axis=0) ----------------
// BIT-EXACT vs numpy: sequential d, square and add rounded separately.
__global__ __launch_bounds__(256) void vq_prep_cn(const float* __restrict__ emb,
                                                  float* __restrict__ cn) {
#pragma clang fp contract(off)
    int k = blockIdx.x * 256 + threadIdx.x;  // grid 4
    float s = 0.f;
    for (int d = 0; d < DIM; ++d) {
        float v = emb[d * KCODE + k];
        float sq = v * v;
        s = s + sq;
    }
    cn[k] = s;
}

// ---------------- main: f16 MFMA distances + argmin + margin flag ----------
// D[code][row] = sum_d E[code][d] * x[row][d] via mfma_f32_16x16x32_f16.
// A = E chunk in LDS (layout [code][d], stride 264 f16, bank-even).
// B = x rows in REGISTERS (wave owns 64 rows, full K=256 -> 128 VGPRs).
// FROZEN: this kernel's skeleton is verified at ~93us. Three restructures
// (row-repartition x2, LDS double-buffer) each produced corrupted distances
// on hardware despite bit-identical per-(row,code) arithmetic on paper;
// the one passing restructure (code-split, R4) gave zero speedup. Do NOT
// restructure staging/barriers/register shapes.
// score s = cn[code] - 2*sim (row-constant ||x||^2 dropped; rescue re-adds).
__global__ __launch_bounds__(256) void vq_argmin(const float* __restrict__ x,
                                                 const _Float16* __restrict__ ef,
                                                 const float* __restrict__ cn,
                                                 int* __restrict__ idx_out,
                                                 int* __restrict__ counter,
                                                 int* __restrict__ list) {
    __shared__ _Float16 Elds[64 * 264];   // 33 KB, +16B row pad
    __shared__ float cnlds[KCODE];        // 4 KB

    const int tid  = threadIdx.x;
    const int lane = tid & 63;
    const int wave = tid >> 6;
    const int lo   = lane & 15;      // row-in-tile / code-in-tile low bits
    const int q    = lane >> 4;      // k-quad (0..3)
    const int n0   = blockIdx.x * 256 + wave * 64;   // wave's first row

    // stage cn once
#pragma unroll
    for (int i = 0; i < 4; ++i) cnlds[tid + i * 256] = cn[tid + i * 256];

    // ---- load x rows into B-fragments (f16, registers) ----
    // B[k=d][n=row]: n = lane&15 within ntile, k = q*8 + j within kstep*32
    half8 xb[4][8];   // [ntile][kstep] = 128 VGPRs
#pragma unroll
    for (int nt = 0; nt < 4; ++nt) {
        const float* rowp = x + (size_t)(n0 + nt * 16 + lo) * DIM + q * 8;
#pragma unroll
        for (int ks = 0; ks < 8; ++ks) {
            float4 a = *(const float4*)(rowp + ks * 32);
            float4 b = *(const float4*)(rowp + ks * 32 + 4);
            half8 h;
            h[0] = (_Float16)a.x; h[1] = (_Float16)a.y;
            h[2] = (_Float16)a.z; h[3] = (_Float16)a.w;
            h[4] = (_Float16)b.x; h[5] = (_Float16)b.y;
            h[6] = (_Float16)b.z; h[7] = (_Float16)b.w;
            xb[nt][ks] = h;
        }
    }

    float best[4], sec[4];
    int   bidx[4];
#pragma unroll
    for (int nt = 0; nt < 4; ++nt) {
        best[nt] = 3.402823466e38f; sec[nt] = 3.402823466e38f; bidx[nt] = 0;
    }

    // prefetch E chunk 0: 64 codes x 256 d f16 = 32 KB; 8x16B per thread
    float4 pf[8];
#pragma unroll
    for (int i = 0; i < 8; ++i) {
        int c = i * 256 + tid;                    // chunk id (code = c>>5, col = c&31)
        pf[i] = *(const float4*)&ef[(size_t)(c >> 5) * DIM + (c & 31) * 8];
    }

    for (int s = 0; s < 16; ++s) {                // 16 super-chunks of 64 codes
        __syncthreads();                          // prior chunk reads done
#pragma unroll
        for (int i = 0; i < 8; ++i) {
            int c = i * 256 + tid;
            *(float4*)&Elds[(c >> 5) * 264 + (c & 31) * 8] = pf[i];
        }
        if (s < 15) {
#pragma unroll
            for (int i = 0; i < 8; ++i) {
                int c = i * 256 + tid;
                pf[i] = *(const float4*)&ef[(size_t)((s + 1) * 64 + (c >> 5)) * DIM + (c & 31) * 8];
            }
        }
        __syncthreads();

#pragma unroll
        for (int ktl = 0; ktl < 2; ++ktl) {       // 2 code-tiles of 32 per chunk
            f32x4 acc[2][4];
#pragma unroll
            for (int m = 0; m < 2; ++m)
#pragma unroll
                for (int nt = 0; nt < 4; ++nt)
                    acc[m][nt] = (f32x4){0.f, 0.f, 0.f, 0.f};

#pragma unroll
            for (int ks = 0; ks < 8; ++ks) {
                half8 ea0 = *(half8*)&Elds[(ktl * 32 + lo) * 264 + ks * 32 + q * 8];
                half8 ea1 = *(half8*)&Elds[(ktl * 32 + 16 + lo) * 264 + ks * 32 + q * 8];
#pragma unroll
                for (int nt = 0; nt < 4; ++nt) {
                    acc[0][nt] = __builtin_amdgcn_mfma_f32_16x16x32_f16(ea0, xb[nt][ks], acc[0][nt], 0, 0, 0);
                    acc[1][nt] = __builtin_amdgcn_mfma_f32_16x16x32_f16(ea1, xb[nt][ks], acc[1][nt], 0, 0, 0);
                }
            }
            // epilogue: fold 32 codes into running best/sec per row
            int cb = s * 64 + ktl * 32;
#pragma unroll
            for (int m = 0; m < 2; ++m) {
                int cbase = cb + m * 16 + q * 4;   // C/D: code = (lane>>4)*4 + reg
                f32x4 cnv = *(f32x4*)&cnlds[cbase];
#pragma unroll
                for (int nt = 0; nt < 4; ++nt) {
#pragma unroll
                    for (int r = 0; r < 4; ++r) {
                        float sd = __builtin_fmaf(-2.f, acc[m][nt][r], cnv[r]);
                        bool lt = sd < best[nt];
                        sec[nt]  = fminf(sec[nt], fmaxf(best[nt], sd));
                        bidx[nt] = lt ? (cbase + r) : bidx[nt];
                        best[nt] = fminf(best[nt], sd);
                    }
                }
            }
        }
    }

    // cross-lane merge: row candidates live in lanes {lo, lo+16, lo+32, lo+48}
#pragma unroll
    for (int nt = 0; nt < 4; ++nt) {
        float b = best[nt], sc = sec[nt];
        int   id = bidx[nt];
#pragma unroll
        for (int off = 16; off <= 32; off <<= 1) {
            float b2 = __shfl_xor(b, off);
            float s2 = __shfl_xor(sc, off);
            int   i2 = __shfl_xor(id, off);
            sc = fminf(fminf(sc, s2), fmaxf(b, b2));
            id = (b2 < b) ? i2 : id;   // exact tie -> flagged below, rescue fixes
            b  = fminf(b, b2);
        }
        if (lane < 16) {
            int row = n0 + nt * 16 + lane;
            idx_out[row] = id;
            if (sc - b < MARGIN) {
                int p = atomicAdd(counter, 1);
                if (p < NROWS) list[p] = row;
            }
        }
    }
}

// ---------------- np-exact rescue for flagged rows (grouped, emb-reuse) ----
// Recomputes all 1024 dists with numpy's exact fp32 pipeline:
// rn via pairwise/AVX512 tree, sim via sequential fmaf, dist = fl(fl(rn+cn)-2s).
// v3: RG=16 rows per emb stream (was 8; R0->R1 with 8 gave -52.6us; rescue
// still ~56us by ledger math -> halve emb L2 traffic again). Each thread owns
// 4 CONSECUTIVE codes (float4 emb loads) x 16 rows = 64 interleaved exact
// sequential-d fmaf chains. Per-(row,code) rounding order unchanged.
__global__ __launch_bounds__(256) void vq_rescue(const float* __restrict__ x,
                                                 const float* __restrict__ emb,
                                                 const float* __restrict__ cn,
                                                 const int* __restrict__ list,
                                                 const int* __restrict__ counter,
                                                 int* __restrict__ idx) {
#pragma clang fp contract(off)
    __shared__ float xs[RG][DIM];     // 16 KB
    __shared__ float rnL[RG];
    __shared__ int   rowL[RG];
    __shared__ float bvA[RG][256];    // 16 KB
    __shared__ int   bkA[RG][256];    // 16 KB
    int cnt = counter[0];
    if (cnt > NROWS) cnt = NROWS;
    const int ngroups = (cnt + RG - 1) / RG;
    const int tid = threadIdx.x;

    for (int g = blockIdx.x; g < ngroups; g += gridDim.x) {
        int base = g * RG;
        int nr = cnt - base; if (nr > RG) nr = RG;
        __syncthreads();                 // protect LDS from prev-iter readers
        if (tid < RG) {
            int li = base + (tid < nr ? tid : 0);   // dup row0 for tail slots
            rowL[tid] = list[li];
        }
        __syncthreads();
        // stage x rows: thread -> row tid>>4, 16 floats at (tid&15)*16
        {
            int rr = tid >> 4;
            int dd = (tid & 15) * 16;
            const float* p = x + (size_t)rowL[rr] * DIM + dd;
            float4 a = *(const float4*)p;
            float4 b = *(const float4*)(p + 4);
            float4 c = *(const float4*)(p + 8);
            float4 d = *(const float4*)(p + 12);
            *(float4*)&xs[rr][dd]      = a;
            *(float4*)&xs[rr][dd + 4]  = b;
            *(float4*)&xs[rr][dd + 8]  = c;
            *(float4*)&xs[rr][dd + 12] = d;
        }
        __syncthreads();
        // rn per row: numpy pairwise(256)=128+128, AVX512 16-lane tree.
        // 16 rows x 16 lanes = all 256 threads; rr = tid>>4, l = tid&15.
        {
            int rr = tid >> 4;
            int l  = tid & 15;
            float blk[2];
#pragma unroll
            for (int b = 0; b < 2; ++b) {
                const float* p = &xs[rr][0] + b * 128 + l;
                float a0 = p[0],  a4 = p[64];
                float a1 = p[16], a5 = p[80];
                float a2 = p[32], a6 = p[96];
                float a3 = p[48], a7 = p[112];
                float s0 = a0 * a0, s4 = a4 * a4;
                float s1 = a1 * a1, s5 = a5 * a5;
                float s2 = a2 * a2, s6 = a6 * a6;
                float s3 = a3 * a3, s7 = a7 * a7;
                float r0 = s0 + s4;
                float r1 = s1 + s5;
                float r2 = s2 + s6;
                float r3 = s3 + s7;
                float v = (r0 + r1) + (r2 + r3);
                float u = v + __shfl_down(v, 8, 16);
                float w = u + __shfl_down(u, 4, 16);
                float t = w + __shfl_down(w, 2, 16);
                float z = t + __shfl_down(t, 1, 16);
                blk[b] = z;
            }
            if (l == 0) rnL[rr] = blk[0] + blk[1];
        }
        __syncthreads();

        // main: 4 consecutive codes (4*tid..4*tid+3) x RG rows, one d pass.
        // Each (rr,c) chain applies d ascending -> bit-exact sequential fmaf.
        float sim[RG][4];
#pragma unroll
        for (int rr = 0; rr < RG; ++rr)
#pragma unroll
            for (int c = 0; c < 4; ++c) sim[rr][c] = 0.f;

        const float* ep = emb + 4 * tid;
#pragma unroll 2
        for (int d0 = 0; d0 < DIM; d0 += 4) {
            float4 e0 = *(const float4*)(ep + (size_t)(d0 + 0) * KCODE);
            float4 e1 = *(const float4*)(ep + (size_t)(d0 + 1) * KCODE);
            float4 e2 = *(const float4*)(ep + (size_t)(d0 + 2) * KCODE);
            float4 e3 = *(const float4*)(ep + (size_t)(d0 + 3) * KCODE);
#pragma unroll
            for (int rr = 0; rr < RG; ++rr) {
                float4 xv = *(const float4*)&xs[rr][d0];
                sim[rr][0] = __builtin_fmaf(xv.x, e0.x, sim[rr][0]);
                sim[rr][1] = __builtin_fmaf(xv.x, e0.y, sim[rr][1]);
                sim[rr][2] = __builtin_fmaf(xv.x, e0.z, sim[rr][2]);
                sim[rr][3] = __builtin_fmaf(xv.x, e0.w, sim[rr][3]);
                sim[rr][0] = __builtin_fmaf(xv.y, e1.x, sim[rr][0]);
                sim[rr][1] = __builtin_fmaf(xv.y, e1.y, sim[rr][1]);
                sim[rr][2] = __builtin_fmaf(xv.y, e1.z, sim[rr][2]);
                sim[rr][3] = __builtin_fmaf(xv.y, e1.w, sim[rr][3]);
                sim[rr][0] = __builtin_fmaf(xv.z, e2.x, sim[rr][0]);
                sim[rr][1] = __builtin_fmaf(xv.z, e2.y, sim[rr][1]);
                sim[rr][2] = __builtin_fmaf(xv.z, e2.z, sim[rr][2]);
                sim[rr][3] = __builtin_fmaf(xv.z, e2.w, sim[rr][3]);
                sim[rr][0] = __builtin_fmaf(xv.w, e3.x, sim[rr][0]);
                sim[rr][1] = __builtin_fmaf(xv.w, e3.y, sim[rr][1]);
                sim[rr][2] = __builtin_fmaf(xv.w, e3.z, sim[rr][2]);
                sim[rr][3] = __builtin_fmaf(xv.w, e3.w, sim[rr][3]);
            }
        }

        // dist + per-thread best (codes ascending -> strict < keeps lowest k)
        float4 cn4 = *(const float4*)&cn[4 * tid];
#pragma unroll
        for (int rr = 0; rr < RG; ++rr) {
            float rnv = rnL[rr];
            float bvl = 3.402823466e38f;
            int   bkl = 0;
#pragma unroll
            for (int c = 0; c < 4; ++c) {
                float t    = rnv + cn4[c];               // fl(rn + cn)
                float dist = t - 2.f * sim[rr][c];       // one rounding
                if (dist < bvl) { bvl = dist; bkl = 4 * tid + c; }
            }
            bvA[rr][tid] = bvl;
            bkA[rr][tid] = bkl;
        }
        __syncthreads();
        // reduce: thread -> row tid>>4, col tid&15; serial-16 then 16-lane
        // shfl tree. min-with-lowest-k comparator is associative.
        {
            int rr = tid >> 4;
            int c  = tid & 15;
            float b = bvA[rr][c];
            int   k = bkA[rr][c];
#pragma unroll
            for (int j = 1; j < 16; ++j) {
                float b2 = bvA[rr][c + 16 * j];
                int   k2 = bkA[rr][c + 16 * j];
                if (b2 < b || (b2 == b && k2 < k)) { b = b2; k = k2; }
            }
#pragma unroll
            for (int off = 8; off >= 1; off >>= 1) {
                float b2 = __shfl_xor(b, off);
                int   k2 = __shfl_xor(k, off);
                if (b2 < b || (b2 == b && k2 < k)) { b = b2; k = k2; }
            }
            if (c == 0 && rr < nr) idx[rowL[rr]] = k;
        }
    }
}

// ---------------- gather + loss (grid-stride, 1 atomic/block) ----------------
__global__ __launch_bounds__(256) void vq_gather(const float* __restrict__ x,
                                                 const float* __restrict__ et,
                                                 const int* __restrict__ idx,
                                                 float* __restrict__ out,
                                                 float* __restrict__ loss_acc) {
    const int tid = threadIdx.x;
    float lsum = 0.f;
#pragma unroll
    for (int it = 0; it < 8; ++it) {
        size_t g   = (size_t)blockIdx.x * 256 + tid + (size_t)it * (2048 * 256);
        int    row = (int)(g >> 6);          // 64 float4 per row
        int    d4  = (int)(g & 63);
        int    k   = idx[row];               // wave-uniform broadcast
        float4 q4  = *(const float4*)&et[(size_t)k * DIM + d4 * 4];
        float4 x4  = *(const float4*)&x[g * 4];
        float d0 = q4.x - x4.x, d1 = q4.y - x4.y;
        float d2 = q4.z - x4.z, d3 = q4.w - x4.w;
        float4 o4 = make_float4(x4.x + d0, x4.y + d1, x4.z + d2, x4.w + d3);
        *(float4*)&out[g * 4] = o4;
        lsum += d0 * d0 + d1 * d1 + d2 * d2 + d3 * d3;
    }
#pragma unroll
    for (int off = 32; off > 0; off >>= 1) lsum += __shfl_down(lsum, off);
    __shared__ float w4[4];
    if ((tid & 63) == 0) w4[tid >> 6] = lsum;
    __syncthreads();
    if (tid == 0) atomicAdd(loss_acc, w4[0] + w4[1] + w4[2] + w4[3]);
}

__global__ void vq_finalize(const float* __restrict__ loss_acc,
                            float* __restrict__ out) {
    // loss = (BETA + 1) * mean((q-x)^2) = 1.25 * sum / NUMEL
    out[NUMEL] = 1.25f * loss_acc[0] / 16777216.f;
}

// ---------------- launch ----------------
extern "C" void kernel_launch(void* const* d_in, const int* in_sizes, int n_in,
                              void* d_out, int out_size, void* d_ws, size_t ws_size,
                              hipStream_t stream) {
    const float* x   = (const float*)d_in[0];   // [65536][256]
    const float* emb = (const float*)d_in[1];   // [256][1024]
    float* out = (float*)d_out;                 // [NUMEL] quantized + [1] loss

    // ws: et 1MB | ef16 512KB | cn 4KB | idx 256KB | loss 4 | counter 4 | list 256KB
    char* ws = (char*)d_ws;
    size_t off = 0;
    float*     et       = (float*)(ws + off);     off += (size_t)KCODE * DIM * 4;
    _Float16*  ef       = (_Float16*)(ws + off);  off += (size_t)KCODE * DIM * 2;
    float*     cn       = (float*)(ws + off);     off += KCODE * 4;
    int*       idx      = (int*)(ws + off);       off += (size_t)NROWS * 4;
    float*     loss_acc = (float*)(ws + off);     off += 4;
    int*       counter  = (int*)(ws + off);       off += 4;
    int*       list     = (int*)(ws + off);

    hipMemsetAsync(loss_acc, 0, 8, stream);      // zero loss + counter
    vq_prep_te<<<256,  256, 0, stream>>>(emb, et, ef);
    vq_prep_cn<<<4,    256, 0, stream>>>(emb, cn);
    vq_argmin <<<256,  256, 0, stream>>>(x, ef, cn, idx, counter, list);
    vq_rescue <<<1024, 256, 0, stream>>>(x, emb, cn, list, counter, idx);
    vq_gather <<<2048, 256, 0, stream>>>(x, et, idx, out, loss_acc);
    vq_finalize<<<1, 1, 0, stream>>>(loss_acc, out);
}

// Round 8
// 270.815 us; speedup vs baseline: 1.0593x; 1.0593x over previous
//
#include <hip/hip_runtime.h>
#include <hip/hip_bf16.h>

// Problem constants (fixed shapes from setup_inputs)
#define NROWS 65536   // 64*32*32
#define DIM   256
#define KCODE 1024
#define NUMEL (NROWS * DIM)   // 16777216
#define MARGIN 0.25f          // ~8 sigma of f16-MFMA distance noise
#define RG 8                  // rescue: flagged rows per block-group
                              // (RG=16 tried R7: +15us regression — register
                              // pressure/latency beats the L2 reuse gain; L2
                              // axis is already saturated at RG=8. Keep 8.)

typedef _Float16 half8 __attribute__((ext_vector_type(8)));
typedef float    f32x4 __attribute__((ext_vector_type(4)));

// ---------------- prep: E^T fp32 (gather) + E^T f16 (MFMA) ----------------
// emb [DIM][KCODE] row-major -> et [KCODE][DIM] fp32, ef [KCODE][DIM] f16
__global__ __launch_bounds__(256) void vq_prep_te(const float* __restrict__ emb,
                                                  float* __restrict__ et,
                                                  _Float16* __restrict__ ef) {
    __shared__ float t[32][33];
    int bk = blockIdx.x & 31;   // k-tile
    int bd = blockIdx.x >> 5;   // d-tile
    int lx = threadIdx.x & 31;
    int ly = threadIdx.x >> 5;
#pragma unroll
    for (int i = 0; i < 4; ++i)
        t[ly + i * 8][lx] = emb[(bd * 32 + ly + i * 8) * KCODE + bk * 32 + lx];
    __syncthreads();
#pragma unroll
    for (int i = 0; i < 4; ++i) {
        float v = t[lx][ly + i * 8];
        int o = (bk * 32 + ly + i * 8) * DIM + bd * 32 + lx;
        et[o] = v;
        ef[o] = (_Float16)v;   // RNE
    }
}

// ---------------- prep: cn[k] = np.sum(emb*emb, axis=0) ----------------
// BIT-EXACT vs numpy: sequential d, square and add rounded separately.
__global__ __launch_bounds__(256) void vq_prep_cn(const float* __restrict__ emb,
                                                  float* __restrict__ cn) {
#pragma clang fp contract(off)
    int k = blockIdx.x * 256 + threadIdx.x;  // grid 4
    float s = 0.f;
    for (int d = 0; d < DIM; ++d) {
        float v = emb[d * KCODE + k];
        float sq = v * v;
        s = s + sq;
    }
    cn[k] = s;
}

// ---------------- main: f16 MFMA distances + argmin + margin flag ----------
// D[code][row] = sum_d E[code][d] * x[row][d] via mfma_f32_16x16x32_f16.
// A = E chunk in LDS (layout [code][d], stride 264 f16, bank-even).
// B = x rows in REGISTERS (wave owns 64 rows, full K=256 -> 128 VGPRs).
// FROZEN: this kernel's skeleton is verified at ~93us. Three restructures
// (row-repartition x2, LDS double-buffer) each produced corrupted distances
// on hardware despite bit-identical per-(row,code) arithmetic on paper;
// the one passing restructure (code-split, R4) gave zero speedup. Do NOT
// restructure staging/barriers/register shapes.
// score s = cn[code] - 2*sim (row-constant ||x||^2 dropped; rescue re-adds).
__global__ __launch_bounds__(256) void vq_argmin(const float* __restrict__ x,
                                                 const _Float16* __restrict__ ef,
                                                 const float* __restrict__ cn,
                                                 int* __restrict__ idx_out,
                                                 int* __restrict__ counter,
                                                 int* __restrict__ list) {
    __shared__ _Float16 Elds[64 * 264];   // 33 KB, +16B row pad
    __shared__ float cnlds[KCODE];        // 4 KB

    const int tid  = threadIdx.x;
    const int lane = tid & 63;
    const int wave = tid >> 6;
    const int lo   = lane & 15;      // row-in-tile / code-in-tile low bits
    const int q    = lane >> 4;      // k-quad (0..3)
    const int n0   = blockIdx.x * 256 + wave * 64;   // wave's first row

    // stage cn once
#pragma unroll
    for (int i = 0; i < 4; ++i) cnlds[tid + i * 256] = cn[tid + i * 256];

    // ---- load x rows into B-fragments (f16, registers) ----
    // B[k=d][n=row]: n = lane&15 within ntile, k = q*8 + j within kstep*32
    half8 xb[4][8];   // [ntile][kstep] = 128 VGPRs
#pragma unroll
    for (int nt = 0; nt < 4; ++nt) {
        const float* rowp = x + (size_t)(n0 + nt * 16 + lo) * DIM + q * 8;
#pragma unroll
        for (int ks = 0; ks < 8; ++ks) {
            float4 a = *(const float4*)(rowp + ks * 32);
            float4 b = *(const float4*)(rowp + ks * 32 + 4);
            half8 h;
            h[0] = (_Float16)a.x; h[1] = (_Float16)a.y;
            h[2] = (_Float16)a.z; h[3] = (_Float16)a.w;
            h[4] = (_Float16)b.x; h[5] = (_Float16)b.y;
            h[6] = (_Float16)b.z; h[7] = (_Float16)b.w;
            xb[nt][ks] = h;
        }
    }

    float best[4], sec[4];
    int   bidx[4];
#pragma unroll
    for (int nt = 0; nt < 4; ++nt) {
        best[nt] = 3.402823466e38f; sec[nt] = 3.402823466e38f; bidx[nt] = 0;
    }

    // prefetch E chunk 0: 64 codes x 256 d f16 = 32 KB; 8x16B per thread
    float4 pf[8];
#pragma unroll
    for (int i = 0; i < 8; ++i) {
        int c = i * 256 + tid;                    // chunk id (code = c>>5, col = c&31)
        pf[i] = *(const float4*)&ef[(size_t)(c >> 5) * DIM + (c & 31) * 8];
    }

    for (int s = 0; s < 16; ++s) {                // 16 super-chunks of 64 codes
        __syncthreads();                          // prior chunk reads done
#pragma unroll
        for (int i = 0; i < 8; ++i) {
            int c = i * 256 + tid;
            *(float4*)&Elds[(c >> 5) * 264 + (c & 31) * 8] = pf[i];
        }
        if (s < 15) {
#pragma unroll
            for (int i = 0; i < 8; ++i) {
                int c = i * 256 + tid;
                pf[i] = *(const float4*)&ef[(size_t)((s + 1) * 64 + (c >> 5)) * DIM + (c & 31) * 8];
            }
        }
        __syncthreads();

#pragma unroll
        for (int ktl = 0; ktl < 2; ++ktl) {       // 2 code-tiles of 32 per chunk
            f32x4 acc[2][4];
#pragma unroll
            for (int m = 0; m < 2; ++m)
#pragma unroll
                for (int nt = 0; nt < 4; ++nt)
                    acc[m][nt] = (f32x4){0.f, 0.f, 0.f, 0.f};

#pragma unroll
            for (int ks = 0; ks < 8; ++ks) {
                half8 ea0 = *(half8*)&Elds[(ktl * 32 + lo) * 264 + ks * 32 + q * 8];
                half8 ea1 = *(half8*)&Elds[(ktl * 32 + 16 + lo) * 264 + ks * 32 + q * 8];
#pragma unroll
                for (int nt = 0; nt < 4; ++nt) {
                    acc[0][nt] = __builtin_amdgcn_mfma_f32_16x16x32_f16(ea0, xb[nt][ks], acc[0][nt], 0, 0, 0);
                    acc[1][nt] = __builtin_amdgcn_mfma_f32_16x16x32_f16(ea1, xb[nt][ks], acc[1][nt], 0, 0, 0);
                }
            }
            // epilogue: fold 32 codes into running best/sec per row
            int cb = s * 64 + ktl * 32;
#pragma unroll
            for (int m = 0; m < 2; ++m) {
                int cbase = cb + m * 16 + q * 4;   // C/D: code = (lane>>4)*4 + reg
                f32x4 cnv = *(f32x4*)&cnlds[cbase];
#pragma unroll
                for (int nt = 0; nt < 4; ++nt) {
#pragma unroll
                    for (int r = 0; r < 4; ++r) {
                        float sd = __builtin_fmaf(-2.f, acc[m][nt][r], cnv[r]);
                        bool lt = sd < best[nt];
                        sec[nt]  = fminf(sec[nt], fmaxf(best[nt], sd));
                        bidx[nt] = lt ? (cbase + r) : bidx[nt];
                        best[nt] = fminf(best[nt], sd);
                    }
                }
            }
        }
    }

    // cross-lane merge: row candidates live in lanes {lo, lo+16, lo+32, lo+48}
#pragma unroll
    for (int nt = 0; nt < 4; ++nt) {
        float b = best[nt], sc = sec[nt];
        int   id = bidx[nt];
#pragma unroll
        for (int off = 16; off <= 32; off <<= 1) {
            float b2 = __shfl_xor(b, off);
            float s2 = __shfl_xor(sc, off);
            int   i2 = __shfl_xor(id, off);
            sc = fminf(fminf(sc, s2), fmaxf(b, b2));
            id = (b2 < b) ? i2 : id;   // exact tie -> flagged below, rescue fixes
            b  = fminf(b, b2);
        }
        if (lane < 16) {
            int row = n0 + nt * 16 + lane;
            idx_out[row] = id;
            if (sc - b < MARGIN) {
                int p = atomicAdd(counter, 1);
                if (p < NROWS) list[p] = row;
            }
        }
    }
}

// ---------------- np-exact rescue for flagged rows (grouped, emb-reuse) ----
// Recomputes all 1024 dists with numpy's exact fp32 pipeline:
// rn via pairwise/AVX512 tree, sim via sequential fmaf, dist = fl(fl(rn+cn)-2s).
// Each block processes RG=8 flagged rows per emb stream (8x emb L2 reuse).
// Each thread owns 4 CONSECUTIVE codes (float4 emb loads) x 8 rows = 32
// interleaved exact sequential-d fmaf chains. Rounding order unchanged.
__global__ __launch_bounds__(256) void vq_rescue(const float* __restrict__ x,
                                                 const float* __restrict__ emb,
                                                 const float* __restrict__ cn,
                                                 const int* __restrict__ list,
                                                 const int* __restrict__ counter,
                                                 int* __restrict__ idx) {
#pragma clang fp contract(off)
    __shared__ float xs[RG][DIM];     // 8 KB
    __shared__ float rnL[RG];
    __shared__ int   rowL[RG];
    __shared__ float bvA[RG][256];    // 8 KB
    __shared__ int   bkA[RG][256];    // 8 KB
    int cnt = counter[0];
    if (cnt > NROWS) cnt = NROWS;
    const int ngroups = (cnt + RG - 1) / RG;
    const int tid = threadIdx.x;

    for (int g = blockIdx.x; g < ngroups; g += gridDim.x) {
        int base = g * RG;
        int nr = cnt - base; if (nr > RG) nr = RG;
        __syncthreads();                 // protect LDS from prev-iter readers
        if (tid < RG) {
            int li = base + (tid < nr ? tid : 0);   // dup row0 for tail slots
            rowL[tid] = list[li];
        }
        __syncthreads();
        // stage x rows: thread -> row tid>>5, 8 floats at (tid&31)*8
        {
            int rr = tid >> 5;
            int dd = (tid & 31) * 8;
            const float* p = x + (size_t)rowL[rr] * DIM + dd;
            float4 a = *(const float4*)p;
            float4 b = *(const float4*)(p + 4);
            *(float4*)&xs[rr][dd]     = a;
            *(float4*)&xs[rr][dd + 4] = b;
        }
        __syncthreads();
        // rn per row: numpy pairwise(256)=128+128, AVX512 16-lane tree.
        // rows in parallel: threads 0..127, rr = tid>>4, lane l = tid&15.
        if (tid < RG * 16) {
            int rr = tid >> 4;
            int l  = tid & 15;
            float blk[2];
#pragma unroll
            for (int b = 0; b < 2; ++b) {
                const float* p = &xs[rr][0] + b * 128 + l;
                float a0 = p[0],  a4 = p[64];
                float a1 = p[16], a5 = p[80];
                float a2 = p[32], a6 = p[96];
                float a3 = p[48], a7 = p[112];
                float s0 = a0 * a0, s4 = a4 * a4;
                float s1 = a1 * a1, s5 = a5 * a5;
                float s2 = a2 * a2, s6 = a6 * a6;
                float s3 = a3 * a3, s7 = a7 * a7;
                float r0 = s0 + s4;
                float r1 = s1 + s5;
                float r2 = s2 + s6;
                float r3 = s3 + s7;
                float v = (r0 + r1) + (r2 + r3);
                float u = v + __shfl_down(v, 8, 16);
                float w = u + __shfl_down(u, 4, 16);
                float t = w + __shfl_down(w, 2, 16);
                float z = t + __shfl_down(t, 1, 16);
                blk[b] = z;
            }
            if (l == 0) rnL[rr] = blk[0] + blk[1];
        }
        __syncthreads();

        // main: 4 consecutive codes (4*tid..4*tid+3) x RG rows, one d pass.
        // Each (rr,c) chain applies d ascending -> bit-exact sequential fmaf.
        float sim[RG][4];
#pragma unroll
        for (int rr = 0; rr < RG; ++rr)
#pragma unroll
            for (int c = 0; c < 4; ++c) sim[rr][c] = 0.f;

        const float* ep = emb + 4 * tid;
#pragma unroll 2
        for (int d0 = 0; d0 < DIM; d0 += 4) {
            float4 e0 = *(const float4*)(ep + (size_t)(d0 + 0) * KCODE);
            float4 e1 = *(const float4*)(ep + (size_t)(d0 + 1) * KCODE);
            float4 e2 = *(const float4*)(ep + (size_t)(d0 + 2) * KCODE);
            float4 e3 = *(const float4*)(ep + (size_t)(d0 + 3) * KCODE);
#pragma unroll
            for (int rr = 0; rr < RG; ++rr) {
                float4 xv = *(const float4*)&xs[rr][d0];
                sim[rr][0] = __builtin_fmaf(xv.x, e0.x, sim[rr][0]);
                sim[rr][1] = __builtin_fmaf(xv.x, e0.y, sim[rr][1]);
                sim[rr][2] = __builtin_fmaf(xv.x, e0.z, sim[rr][2]);
                sim[rr][3] = __builtin_fmaf(xv.x, e0.w, sim[rr][3]);
                sim[rr][0] = __builtin_fmaf(xv.y, e1.x, sim[rr][0]);
                sim[rr][1] = __builtin_fmaf(xv.y, e1.y, sim[rr][1]);
                sim[rr][2] = __builtin_fmaf(xv.y, e1.z, sim[rr][2]);
                sim[rr][3] = __builtin_fmaf(xv.y, e1.w, sim[rr][3]);
                sim[rr][0] = __builtin_fmaf(xv.z, e2.x, sim[rr][0]);
                sim[rr][1] = __builtin_fmaf(xv.z, e2.y, sim[rr][1]);
                sim[rr][2] = __builtin_fmaf(xv.z, e2.z, sim[rr][2]);
                sim[rr][3] = __builtin_fmaf(xv.z, e2.w, sim[rr][3]);
                sim[rr][0] = __builtin_fmaf(xv.w, e3.x, sim[rr][0]);
                sim[rr][1] = __builtin_fmaf(xv.w, e3.y, sim[rr][1]);
                sim[rr][2] = __builtin_fmaf(xv.w, e3.z, sim[rr][2]);
                sim[rr][3] = __builtin_fmaf(xv.w, e3.w, sim[rr][3]);
            }
        }

        // dist + per-thread best (codes ascending -> strict < keeps lowest k)
        float4 cn4 = *(const float4*)&cn[4 * tid];
#pragma unroll
        for (int rr = 0; rr < RG; ++rr) {
            float rnv = rnL[rr];
            float bvl = 3.402823466e38f;
            int   bkl = 0;
#pragma unroll
            for (int c = 0; c < 4; ++c) {
                float t    = rnv + cn4[c];               // fl(rn + cn)
                float dist = t - 2.f * sim[rr][c];       // one rounding
                if (dist < bvl) { bvl = dist; bkl = 4 * tid + c; }
            }
            bvA[rr][tid] = bvl;
            bkA[rr][tid] = bkl;
        }
        __syncthreads();
        // reduce: thread -> row tid>>5, col tid&31; serial-8 then 32-lane shfl.
        // min-with-lowest-k comparator is associative -> order-independent.
        {
            int rr = tid >> 5;
            int c  = tid & 31;
            float b = bvA[rr][c];
            int   k = bkA[rr][c];
#pragma unroll
            for (int j = 1; j < 8; ++j) {
                float b2 = bvA[rr][c + 32 * j];
                int   k2 = bkA[rr][c + 32 * j];
                if (b2 < b || (b2 == b && k2 < k)) { b = b2; k = k2; }
            }
#pragma unroll
            for (int off = 16; off >= 1; off >>= 1) {
                float b2 = __shfl_xor(b, off);
                int   k2 = __shfl_xor(k, off);
                if (b2 < b || (b2 == b && k2 < k)) { b = b2; k = k2; }
            }
            if (c == 0 && rr < nr) idx[rowL[rr]] = k;
        }
    }
}

// ---------------- gather + loss (grid-stride, 1 atomic/block) ----------------
__global__ __launch_bounds__(256) void vq_gather(const float* __restrict__ x,
                                                 const float* __restrict__ et,
                                                 const int* __restrict__ idx,
                                                 float* __restrict__ out,
                                                 float* __restrict__ loss_acc) {
    const int tid = threadIdx.x;
    float lsum = 0.f;
#pragma unroll
    for (int it = 0; it < 8; ++it) {
        size_t g   = (size_t)blockIdx.x * 256 + tid + (size_t)it * (2048 * 256);
        int    row = (int)(g >> 6);          // 64 float4 per row
        int    d4  = (int)(g & 63);
        int    k   = idx[row];               // wave-uniform broadcast
        float4 q4  = *(const float4*)&et[(size_t)k * DIM + d4 * 4];
        float4 x4  = *(const float4*)&x[g * 4];
        float d0 = q4.x - x4.x, d1 = q4.y - x4.y;
        float d2 = q4.z - x4.z, d3 = q4.w - x4.w;
        float4 o4 = make_float4(x4.x + d0, x4.y + d1, x4.z + d2, x4.w + d3);
        *(float4*)&out[g * 4] = o4;
        lsum += d0 * d0 + d1 * d1 + d2 * d2 + d3 * d3;
    }
#pragma unroll
    for (int off = 32; off > 0; off >>= 1) lsum += __shfl_down(lsum, off);
    __shared__ float w4[4];
    if ((tid & 63) == 0) w4[tid >> 6] = lsum;
    __syncthreads();
    if (tid == 0) atomicAdd(loss_acc, w4[0] + w4[1] + w4[2] + w4[3]);
}

__global__ void vq_finalize(const float* __restrict__ loss_acc,
                            float* __restrict__ out) {
    // loss = (BETA + 1) * mean((q-x)^2) = 1.25 * sum / NUMEL
    out[NUMEL] = 1.25f * loss_acc[0] / 16777216.f;
}

// ---------------- launch ----------------
extern "C" void kernel_launch(void* const* d_in, const int* in_sizes, int n_in,
                              void* d_out, int out_size, void* d_ws, size_t ws_size,
                              hipStream_t stream) {
    const float* x   = (const float*)d_in[0];   // [65536][256]
    const float* emb = (const float*)d_in[1];   // [256][1024]
    float* out = (float*)d_out;                 // [NUMEL] quantized + [1] loss

    // ws: et 1MB | ef16 512KB | cn 4KB | idx 256KB | loss 4 | counter 4 | list 256KB
    char* ws = (char*)d_ws;
    size_t off = 0;
    float*     et       = (float*)(ws + off);     off += (size_t)KCODE * DIM * 4;
    _Float16*  ef       = (_Float16*)(ws + off);  off += (size_t)KCODE * DIM * 2;
    float*     cn       = (float*)(ws + off);     off += KCODE * 4;
    int*       idx      = (int*)(ws + off);       off += (size_t)NROWS * 4;
    float*     loss_acc = (float*)(ws + off);     off += 4;
    int*       counter  = (int*)(ws + off);       off += 4;
    int*       list     = (int*)(ws + off);

    hipMemsetAsync(loss_acc, 0, 8, stream);      // zero loss + counter
    vq_prep_te<<<256,  256, 0, stream>>>(emb, et, ef);
    vq_prep_cn<<<4,    256, 0, stream>>>(emb, cn);
    vq_argmin <<<256,  256, 0, stream>>>(x, ef, cn, idx, counter, list);
    vq_rescue <<<1024, 256, 0, stream>>>(x, emb, cn, list, counter, idx);
    vq_gather <<<2048, 256, 0, stream>>>(x, et, idx, out, loss_acc);
    vq_finalize<<<1, 1, 0, stream>>>(loss_acc, out);
}